// Round 4
// baseline (68.339 us; speedup 1.0000x reference)
//
#include <hip/hip_runtime.h>
#include <hip/hip_cooperative_groups.h>
#include <math.h>

namespace cg = cooperative_groups;

// Problem constants (match reference setup_inputs)
#define BB 128
#define PP 256
#define CC 1000

#define NCT 63   // blocks; block ct owns c in [16*ct, min(16*ct+16, 1000))

// ws layout (floats) — every slot has exactly ONE writer, no zeroing needed:
//   [0      : 16128)  part_w [ct][p]  ct=0..62, p=0..255   (wsq partials)
//   [16128  : 24192)  part_sq[ct][b]  ct=0..62, b=0..127   (sqrt-of-M partials)
//   [24192  : 32256)  part_fr[ct][b]                        (M row partials)
#define OFF_W  0
#define OFF_SQ 16128
#define OFF_FR 24192

__global__ __launch_bounds__(256) void k_all(const float* __restrict__ W,
                                             const float* __restrict__ S,
                                             float* __restrict__ ws,
                                             float* __restrict__ out) {
    int ct = blockIdx.x;
    int t = threadIdx.x;

    __shared__ float s2s[16][260];     // pad 256->260
    __shared__ float red_sq[16][17];
    __shared__ float red_fr[16][17];

    int c0 = ct * 16;
    int bl = t & 15;   // b within tile
    int cl = t >> 4;   // c within tile
    int c = c0 + cl;
    bool cv = (c < CC);
    const float4* w4 = (const float4*)(W + (cv ? c : 0) * PP);

    // ---- main: for this block's 16 c-rows, loop all 8 b-tiles ----
    for (int bt = 0; bt < 8; ++bt) {
        int b0 = bt * 16;
#pragma unroll
        for (int i = 0; i < 16; ++i) {
            int idx = t + 256 * i;
            int row = idx >> 8, col = idx & 255;
            float s = S[(b0 + row) * PP + col];
            s2s[row][col] = s * s;
        }
        __syncthreads();

        float acc = 0.f;
        if (cv) {
#pragma unroll 4
            for (int p = 0; p < 64; ++p) {
                float4 w = w4[p];  // 16 lanes share c -> broadcast
                float4 s2 = *(const float4*)&s2s[bl][p * 4];
                acc += s2.x * (w.x * w.x);
                acc += s2.y * (w.y * w.y);
                acc += s2.z * (w.z * w.z);
                acc += s2.w * (w.w * w.w);
            }
        }
        red_sq[cl][bl] = cv ? sqrtf(acc) : 0.f;
        red_fr[cl][bl] = acc;
        __syncthreads();

        if (t < 16) {  // t == local b; reduce over the 16 c-lanes
            float ssum = 0.f, fsum = 0.f;
#pragma unroll
            for (int j = 0; j < 16; ++j) {
                ssum += red_sq[j][t];
                fsum += red_fr[j][t];
            }
            ws[OFF_SQ + ct * BB + b0 + t] = ssum;   // unique slot
            ws[OFF_FR + ct * BB + b0 + t] = fsum;   // unique slot
        }
        // no extra barrier needed: next iteration's first __syncthreads orders
        // the red_* reads above against the next tile's red_* writes.
    }

    // ---- wsq partial for this block's c-rows (rows are L2-hot now) ----
    {
        int chi = min(c0 + 16, CC);
        float wa = 0.f;
        for (int cc = c0; cc < chi; ++cc) {
            float w = W[cc * PP + t];  // coalesced across t (= p)
            wa += w * w;
        }
        ws[OFF_W + ct * 256 + t] = wa;  // unique slot
    }

    cg::this_grid().sync();

    // ---- finalize in block 0 ----
    if (ct == 0) {
        __shared__ float sw[PP];
        __shared__ float red[BB];

        float a = 0.f;
#pragma unroll 7
        for (int k = 0; k < NCT; ++k) a += ws[OFF_W + k * 256 + t];
        sw[t] = sqrtf(a);
        __syncthreads();

        if (t < BB) {
            int b = t;
            float ta = 0.f, fsq = 0.f;
            for (int k = 0; k < NCT; ++k) {
                ta  += ws[OFF_SQ + k * BB + b];
                fsq += ws[OFF_FR + k * BB + b];
            }
            float tb = 0.f;
            const float4* s4 = (const float4*)(S + b * PP);
#pragma unroll 8
            for (int p = 0; p < PP / 4; ++p) {
                float4 s = s4[p];
                tb += fabsf(s.x) * sw[p * 4 + 0];
                tb += fabsf(s.y) * sw[p * 4 + 1];
                tb += fabsf(s.z) * sw[p * 4 + 2];
                tb += fabsf(s.w) * sw[p * 4 + 3];
            }
            float inv_scale = 1.0f / sqrtf((float)(PP * CC));
            float sparsity = (ta * ta + tb * tb) / (fsq + 1e-20f);
            sparsity *= inv_scale;
            sparsity += sqrtf(fsq);
            red[b] = sparsity;
        }
        __syncthreads();
        if (t == 0) {
            float sum = 0.f;
            for (int i = 0; i < BB; ++i) sum += red[i];
            out[0] = sum / (float)BB;
        }
    }
}

extern "C" void kernel_launch(void* const* d_in, const int* in_sizes, int n_in,
                              void* d_out, int out_size, void* d_ws, size_t ws_size,
                              hipStream_t stream) {
    const float* W = (const float*)d_in[0];  // [C=1000, P=256]
    const float* S = (const float*)d_in[1];  // [B=128, P=256]
    float* out = (float*)d_out;              // scalar
    float* ws = (float*)d_ws;                // >= 32256 floats (~126 KB)

    void* args[] = {(void*)&W, (void*)&S, (void*)&ws, (void*)&out};
    hipLaunchCooperativeKernel((void*)k_all, dim3(NCT), dim3(256), args, 0, stream);
}